// Round 13
// baseline (641.713 us; speedup 1.0000x reference)
//
#include <hip/hip_runtime.h>
#include <hip/hip_fp16.h>
#include <hip/hip_bf16.h>

typedef __attribute__((ext_vector_type(8)))  short bf16x8;
typedef __attribute__((ext_vector_type(4)))  float f32x4;
typedef __attribute__((ext_vector_type(16))) float f32x16;

constexpr int EMBED = 64;
constexpr int RBF   = 16;
constexpr int SCAN_TILE = 1024;

__device__ __forceinline__ short f2bf(float f) {
    __hip_bfloat16 h = __float2bfloat16(f);   // RNE
    return *reinterpret_cast<short*>(&h);
}
__device__ __forceinline__ float bf2f(short s) {
    unsigned u = ((unsigned)(unsigned short)s) << 16;
    return __uint_as_float(u);
}
__device__ __forceinline__ unsigned pk_bf(float lo, float hi) {
    unsigned l = (unsigned short)f2bf(lo);
    unsigned h = (unsigned short)f2bf(hi);
    return l | (h << 16);
}
__device__ __forceinline__ unsigned pk_f16(float lo, float hi) {
    __half2 h = __halves2half2(__float2half_rn(lo), __float2half_rn(hi));
    return *reinterpret_cast<unsigned*>(&h);
}
__device__ __forceinline__ void atom_pk_add_f16(__half* addr, unsigned data) {
    asm volatile("global_atomic_pk_add_f16 %0, %1, off"
                 :: "v"(addr), "v"(data) : "memory");
}
__device__ __forceinline__ float silu(float x) {
    return x * __builtin_amdgcn_rcpf(1.0f + __expf(-x));
}

// bf16(pi), bf16(pi/2) (r10-validated angle constants)
constexpr float PI_BF  = 3.140625f;
constexpr float PI2_BF = 1.5703125f;

// C/D row map for 32x32 MFMA (r12-validated)
__device__ __forceinline__ int crow(int j, int h) {
    return (j & 3) + 8 * (j >> 2) + 4 * h;
}

// ======================= CSR construction (r6/r7-validated) ================
__global__ __launch_bounds__(256) void k_hist(
    const int* __restrict__ ei, int* __restrict__ counts, int E)
{
    int i = blockIdx.x * 256 + threadIdx.x;
    if (i < E) atomicAdd(&counts[ei[i]], 1);
}

__global__ __launch_bounds__(256) void k_scan1(
    const int* __restrict__ counts, int* __restrict__ offsets,
    int* __restrict__ bsums, int nn)
{
    __shared__ int lds[256];
    const int t = threadIdx.x;
    const int base = blockIdx.x * SCAN_TILE;
    int v[4]; int s = 0;
#pragma unroll
    for (int j = 0; j < 4; ++j) {
        const int i = base + t * 4 + j;
        v[j] = (i < nn) ? counts[i] : 0;
        s += v[j];
    }
    lds[t] = s;
    __syncthreads();
    for (int off = 1; off < 256; off <<= 1) {
        int x = (t >= off) ? lds[t - off] : 0;
        __syncthreads();
        lds[t] += x;
        __syncthreads();
    }
    int run = lds[t] - s;
    if (t == 255) bsums[blockIdx.x] = lds[255];
#pragma unroll
    for (int j = 0; j < 4; ++j) {
        const int i = base + t * 4 + j;
        if (i < nn) offsets[i] = run;
        run += v[j];
    }
}

__global__ void k_scan2(int* __restrict__ bsums, int nblk)
{
    if (threadIdx.x == 0 && blockIdx.x == 0) {
        int a = 0;
        for (int i = 0; i < nblk; ++i) { int t = bsums[i]; bsums[i] = a; a += t; }
    }
}

__global__ __launch_bounds__(256) void k_scan3(
    int* __restrict__ offsets, const int* __restrict__ bsums,
    int* __restrict__ counts, int nn, int Etot)
{
    const int base = blockIdx.x * SCAN_TILE;
    const int add = bsums[blockIdx.x];
#pragma unroll
    for (int j = 0; j < 4; ++j) {
        const int i = base + threadIdx.x * 4 + j;
        if (i < nn) { offsets[i] += add; counts[i] = 0; }   // counts -> cursor
    }
    if (blockIdx.x == 0 && threadIdx.x == 0) offsets[nn] = Etot;
}

// ======================= edge kernel: 32x32 MFMA + sorted stores ===========
// r12 structure; scatter replaced by plain stores to CSR-sorted slots.
// Slot per edge computed in the prologue (1 int atomic per edge).
template <bool GUARD>
__global__ __launch_bounds__(256, 2) void edge_kernel_sort(
    const float* __restrict__ rbf,
    const int* __restrict__ ei,
    const float* __restrict__ W1,
    const float* __restrict__ b1,
    const float* __restrict__ W2,
    const float* __restrict__ b2,
    const int* __restrict__ offsets,
    int* __restrict__ cursor,
    unsigned* __restrict__ smsg,   // E rows x 32 dwords (64 f16 ch each)
    int e_base, int E)
{
    __shared__ __align__(16) short lds_s[4][32 * 64];  // 16 KB
    __shared__ int lds_slot[256];
    __shared__ unsigned char lds_flag[256];
    __shared__ int wave_any[4];

    const int tid  = threadIdx.x;
    const int lane = tid & 63;
    const int wave = tid >> 6;
    const int n = lane & 31;
    const int h = lane >> 5;
    const int blk_e0 = e_base + blockIdx.x * 256;

    // ---- prologue: slot + self-loop flag ----
    {
        const int e = blk_e0 + tid;
        const bool v = !GUARD || (e < E);
        const int row = v ? ei[e] : 0;
        const int col = v ? ei[E + e] : 1;
        int slot = 0;
        if (v) slot = offsets[row] + atomicAdd(&cursor[row], 1);
        lds_slot[tid] = slot;
        const bool fl = v && (row == col);
        lds_flag[tid] = fl;
        const unsigned long long m = __ballot(fl);
        if (lane == 0) wave_any[wave] = (m != 0ull);
    }
    __syncthreads();

    // ---- B fragments + folded biases (r12-validated) ----
    bf16x8 b1f[2];
    float  b1v[2], dlt[2], b2v[2];
#pragma unroll
    for (int hh = 0; hh < 2; ++hh) {
        const int ch = 2 * n + hh;
#pragma unroll
        for (int j = 0; j < 8; ++j)
            b1f[hh][j] = f2bf(W1[(h * 8 + j) * EMBED + ch]);
        const float w16 = bf2f(f2bf(W1[RBF * EMBED + ch]));
        b1v[hh] = b1[ch] + PI_BF * w16;
        dlt[hh] = (PI2_BF - PI_BF) * w16;
        b2v[hh] = b2[ch];
    }
    bf16x8 b2f[4][2];
#pragma unroll
    for (int kk = 0; kk < 4; ++kk)
#pragma unroll
        for (int hh = 0; hh < 2; ++hh) {
            const int ch = 2 * n + hh;
#pragma unroll
            for (int j = 0; j < 8; ++j)
                b2f[kk][hh][j] = f2bf(W2[(kk * 16 + h * 8 + j) * EMBED + ch]);
        }

    char* const sl = reinterpret_cast<char*>(lds_s[wave]);

#pragma unroll 1
    for (int mt = 0; mt < 2; ++mt) {
        const int e0  = blk_e0 + wave * 64 + mt * 32;
        if (GUARD && e0 >= E) break;
        const int el0 = wave * 64 + mt * 32;

        // ---- A1 ----
        bf16x8 a1 = {};
        {
            const int ea = e0 + n;
            if (!GUARD || ea < E) {
                const float4 p0 = *reinterpret_cast<const float4*>(rbf + (long long)ea * RBF + h * 8);
                const float4 p1 = *reinterpret_cast<const float4*>(rbf + (long long)ea * RBF + h * 8 + 4);
                a1[0] = f2bf(p0.x); a1[1] = f2bf(p0.y); a1[2] = f2bf(p0.z); a1[3] = f2bf(p0.w);
                a1[4] = f2bf(p1.x); a1[5] = f2bf(p1.y); a1[6] = f2bf(p1.z); a1[7] = f2bf(p1.w);
            }
        }

        // ---- GEMM1, angle folded into bias ----
        f32x16 accA, accB;
#pragma unroll
        for (int j = 0; j < 16; ++j) { accA[j] = b1v[0]; accB[j] = b1v[1]; }
        accA = __builtin_amdgcn_mfma_f32_32x32x16_bf16(a1, b1f[0], accA, 0, 0, 0);
        accB = __builtin_amdgcn_mfma_f32_32x32x16_bf16(a1, b1f[1], accB, 0, 0, 0);

        if (wave_any[wave]) {
#pragma unroll
            for (int j = 0; j < 16; ++j) {
                const int m = crow(j, h);
                if (lds_flag[el0 + m]) { accA[j] += dlt[0]; accB[j] += dlt[1]; }
            }
        }

        // ---- SiLU + pk-bf16 swizzled LDS write ----
#pragma unroll
        for (int j = 0; j < 16; ++j) {
            const int m = crow(j, h);
            const unsigned u = pk_bf(silu(accA[j]), silu(accB[j]));
            *reinterpret_cast<unsigned*>(sl + m * 128 + ((4 * n) ^ ((m & 7) << 4))) = u;
        }
        __builtin_amdgcn_wave_barrier();

        // ---- GEMM2 ----
        f32x16 acc2A, acc2B;
#pragma unroll
        for (int j = 0; j < 16; ++j) { acc2A[j] = b2v[0]; acc2B[j] = b2v[1]; }
#pragma unroll
        for (int kk = 0; kk < 4; ++kk) {
            const int byte = n * 128 + ((kk * 32 + h * 16) ^ ((n & 7) << 4));
            const bf16x8 a2 = *reinterpret_cast<const bf16x8*>(sl + byte);
            acc2A = __builtin_amdgcn_mfma_f32_32x32x16_bf16(a2, b2f[kk][0], acc2A, 0, 0, 0);
            acc2B = __builtin_amdgcn_mfma_f32_32x32x16_bf16(a2, b2f[kk][1], acc2B, 0, 0, 0);
        }
        __builtin_amdgcn_wave_barrier();

        // ---- sorted stores: edge crow(j,h) -> smsg[slot], 128 B coalesced ----
#pragma unroll
        for (int j = 0; j < 16; ++j) {
            const int m = crow(j, h);
            const int eat = e0 + m;
            if (!GUARD || eat < E) {
                const size_t slot = (size_t)lds_slot[el0 + m];
                smsg[slot * 32u + (unsigned)n] = pk_f16(acc2A[j], acc2B[j]);
            }
        }
    }
}

// ======================= phase 2: streaming segment-sum + node MLP =========
// Wave per node; msgs for node n are contiguous [offsets[n], offsets[n+1])
// -> fully coalesced sequential reads; fp32 accumulation.
__global__ __launch_bounds__(256) void seg_node_kernel(
    const float* __restrict__ x,
    const unsigned* __restrict__ smsg,
    const int* __restrict__ offsets,
    const float* __restrict__ W3, const float* __restrict__ b3,
    const float* __restrict__ W4, const float* __restrict__ b4,
    float* __restrict__ out, int nn)
{
    __shared__ __align__(16) float lds_s[4][EMBED];
    const int lane = threadIdx.x & 63;
    const int wave = threadIdx.x >> 6;
    const int dw = lane & 31;    // channel-pair index within 128-B row
    const int rp = lane >> 5;    // row parity

    float w3c[EMBED], w4c[EMBED];
#pragma unroll
    for (int j = 0; j < EMBED; ++j) w3c[j] = W3[j * EMBED + lane];
#pragma unroll
    for (int j = 0; j < EMBED; ++j) w4c[j] = W4[j * EMBED + lane];
    const float b3v = b3[lane];
    const float b4v = b4[lane];

    const float4* s4 = reinterpret_cast<const float4*>(lds_s[wave]);
    const int wid = blockIdx.x * 4 + wave;
    const int nw  = gridDim.x * 4;

    for (int n = wid; n < nn; n += nw) {
        const int beg = offsets[n];
        const int end = offsets[n + 1];

        float s0 = 0.0f, s1 = 0.0f;
#pragma unroll 4
        for (int j = beg + rp; j < end; j += 2) {
            const unsigned d = smsg[(size_t)j * 32u + (unsigned)dw];
            const __half2 h2 = *reinterpret_cast<const __half2*>(&d);
            s0 += __low2float(h2);
            s1 += __high2float(h2);
        }
        s0 += __shfl_xor(s0, 32, 64);
        s1 += __shfl_xor(s1, 32, 64);

        lds_s[wave][2 * dw]     = s0;
        lds_s[wave][2 * dw + 1] = s1;
        __builtin_amdgcn_wave_barrier();

        float acc = b3v;
#pragma unroll
        for (int j4 = 0; j4 < EMBED / 4; ++j4) {
            const float4 sv = s4[j4];
            acc = fmaf(sv.x, w3c[4 * j4 + 0], acc);
            acc = fmaf(sv.y, w3c[4 * j4 + 1], acc);
            acc = fmaf(sv.z, w3c[4 * j4 + 2], acc);
            acc = fmaf(sv.w, w3c[4 * j4 + 3], acc);
        }
        const float s = acc * __builtin_amdgcn_rcpf(1.0f + __expf(-acc));
        __builtin_amdgcn_wave_barrier();
        lds_s[wave][lane] = s;
        __builtin_amdgcn_wave_barrier();
        float acc2 = b4v;
#pragma unroll
        for (int j4 = 0; j4 < EMBED / 4; ++j4) {
            const float4 sv = s4[j4];
            acc2 = fmaf(sv.x, w4c[4 * j4 + 0], acc2);
            acc2 = fmaf(sv.y, w4c[4 * j4 + 1], acc2);
            acc2 = fmaf(sv.z, w4c[4 * j4 + 2], acc2);
            acc2 = fmaf(sv.w, w4c[4 * j4 + 3], acc2);
        }
        __builtin_amdgcn_wave_barrier();

        const long long base = (long long)n * EMBED + lane;
        out[base] = x[base] + acc2;
    }
}

// ======================= fallback: r12 atomic path (validated) =============
template <bool GUARD, bool F16>
__global__ __launch_bounds__(256, 2) void edge_kernel32(
    const float* __restrict__ rbf, const int* __restrict__ ei,
    const float* __restrict__ W1, const float* __restrict__ b1,
    const float* __restrict__ W2, const float* __restrict__ b2,
    void* __restrict__ agg, int e_base, int E)
{
    __shared__ __align__(16) short lds_s[4][32 * 64];
    __shared__ int lds_row[256];
    __shared__ unsigned char lds_flag[256];
    __shared__ int wave_any[4];
    const int tid = threadIdx.x, lane = tid & 63, wave = tid >> 6;
    const int n = lane & 31, h = lane >> 5;
    const int blk_e0 = e_base + blockIdx.x * 256;
    {
        const int e = blk_e0 + tid;
        const bool v = !GUARD || (e < E);
        const int row = v ? ei[e] : 0;
        const int col = v ? ei[E + e] : 1;
        lds_row[tid] = row;
        const bool fl = v && (row == col);
        lds_flag[tid] = fl;
        const unsigned long long m = __ballot(fl);
        if (lane == 0) wave_any[wave] = (m != 0ull);
    }
    __syncthreads();
    bf16x8 b1f[2];
    float b1v[2], dlt[2], b2v[2];
#pragma unroll
    for (int hh = 0; hh < 2; ++hh) {
        const int ch = 2 * n + hh;
#pragma unroll
        for (int j = 0; j < 8; ++j)
            b1f[hh][j] = f2bf(W1[(h * 8 + j) * EMBED + ch]);
        const float w16 = bf2f(f2bf(W1[RBF * EMBED + ch]));
        b1v[hh] = b1[ch] + PI_BF * w16;
        dlt[hh] = (PI2_BF - PI_BF) * w16;
        b2v[hh] = b2[ch];
    }
    bf16x8 b2f[4][2];
#pragma unroll
    for (int kk = 0; kk < 4; ++kk)
#pragma unroll
        for (int hh = 0; hh < 2; ++hh) {
            const int ch = 2 * n + hh;
#pragma unroll
            for (int j = 0; j < 8; ++j)
                b2f[kk][hh][j] = f2bf(W2[(kk * 16 + h * 8 + j) * EMBED + ch]);
        }
    char* const sl = reinterpret_cast<char*>(lds_s[wave]);
#pragma unroll 1
    for (int mt = 0; mt < 2; ++mt) {
        const int e0 = blk_e0 + wave * 64 + mt * 32;
        if (GUARD && e0 >= E) break;
        const int el0 = wave * 64 + mt * 32;
        bf16x8 a1 = {};
        {
            const int ea = e0 + n;
            if (!GUARD || ea < E) {
                const float4 p0 = *reinterpret_cast<const float4*>(rbf + (long long)ea * RBF + h * 8);
                const float4 p1 = *reinterpret_cast<const float4*>(rbf + (long long)ea * RBF + h * 8 + 4);
                a1[0] = f2bf(p0.x); a1[1] = f2bf(p0.y); a1[2] = f2bf(p0.z); a1[3] = f2bf(p0.w);
                a1[4] = f2bf(p1.x); a1[5] = f2bf(p1.y); a1[6] = f2bf(p1.z); a1[7] = f2bf(p1.w);
            }
        }
        f32x16 accA, accB;
#pragma unroll
        for (int j = 0; j < 16; ++j) { accA[j] = b1v[0]; accB[j] = b1v[1]; }
        accA = __builtin_amdgcn_mfma_f32_32x32x16_bf16(a1, b1f[0], accA, 0, 0, 0);
        accB = __builtin_amdgcn_mfma_f32_32x32x16_bf16(a1, b1f[1], accB, 0, 0, 0);
        if (wave_any[wave]) {
#pragma unroll
            for (int j = 0; j < 16; ++j) {
                const int m = crow(j, h);
                if (lds_flag[el0 + m]) { accA[j] += dlt[0]; accB[j] += dlt[1]; }
            }
        }
#pragma unroll
        for (int j = 0; j < 16; ++j) {
            const int m = crow(j, h);
            const unsigned u = pk_bf(silu(accA[j]), silu(accB[j]));
            *reinterpret_cast<unsigned*>(sl + m * 128 + ((4 * n) ^ ((m & 7) << 4))) = u;
        }
        __builtin_amdgcn_wave_barrier();
        f32x16 acc2A, acc2B;
#pragma unroll
        for (int j = 0; j < 16; ++j) { acc2A[j] = b2v[0]; acc2B[j] = b2v[1]; }
#pragma unroll
        for (int kk = 0; kk < 4; ++kk) {
            const int byte = n * 128 + ((kk * 32 + h * 16) ^ ((n & 7) << 4));
            const bf16x8 a2 = *reinterpret_cast<const bf16x8*>(sl + byte);
            acc2A = __builtin_amdgcn_mfma_f32_32x32x16_bf16(a2, b2f[kk][0], acc2A, 0, 0, 0);
            acc2B = __builtin_amdgcn_mfma_f32_32x32x16_bf16(a2, b2f[kk][1], acc2B, 0, 0, 0);
        }
        __builtin_amdgcn_wave_barrier();
#pragma unroll
        for (int j = 0; j < 16; ++j) {
            const int m = crow(j, h);
            const int eat = e0 + m;
            if (!GUARD || eat < E) {
                const unsigned row = (unsigned)lds_row[el0 + m];
                if (F16) {
                    __half* const dst = reinterpret_cast<__half*>(agg) + row * 64u;
                    atom_pk_add_f16(dst + 2 * n, pk_f16(acc2A[j], acc2B[j]));
                } else {
                    float* const dst = reinterpret_cast<float*>(agg) + row * 64u;
                    atomicAdd(dst + 2 * n,     acc2A[j]);
                    atomicAdd(dst + 2 * n + 1, acc2B[j]);
                }
            }
        }
    }
}

template <bool F16>
__global__ __launch_bounds__(256) void node_kernel(
    const float* __restrict__ x, const void* __restrict__ aggv,
    const float* __restrict__ W3, const float* __restrict__ b3,
    const float* __restrict__ W4, const float* __restrict__ b4,
    float* __restrict__ out, int nn)
{
    __shared__ __align__(16) float lds_s[4][EMBED];
    const int lane = threadIdx.x & 63;
    const int wave = threadIdx.x >> 6;
    float w3c[EMBED], w4c[EMBED];
#pragma unroll
    for (int j = 0; j < EMBED; ++j) w3c[j] = W3[j * EMBED + lane];
#pragma unroll
    for (int j = 0; j < EMBED; ++j) w4c[j] = W4[j * EMBED + lane];
    const float b3v = b3[lane];
    const float b4v = b4[lane];
    const float4* s4 = reinterpret_cast<const float4*>(lds_s[wave]);
    const int wid = blockIdx.x * 4 + wave;
    const int nw  = gridDim.x * 4;
    for (int n = wid; n < nn; n += nw) {
        const long long base = (long long)n * EMBED + lane;
        float a;
        if (F16) a = __half2float(reinterpret_cast<const __half*>(aggv)[base]);
        else     a = reinterpret_cast<const float*>(aggv)[base];
        lds_s[wave][lane] = a;
        __builtin_amdgcn_wave_barrier();
        float acc = b3v;
#pragma unroll
        for (int j4 = 0; j4 < EMBED / 4; ++j4) {
            const float4 sv = s4[j4];
            acc = fmaf(sv.x, w3c[4 * j4 + 0], acc);
            acc = fmaf(sv.y, w3c[4 * j4 + 1], acc);
            acc = fmaf(sv.z, w3c[4 * j4 + 2], acc);
            acc = fmaf(sv.w, w3c[4 * j4 + 3], acc);
        }
        const float s = acc * __builtin_amdgcn_rcpf(1.0f + __expf(-acc));
        __builtin_amdgcn_wave_barrier();
        lds_s[wave][lane] = s;
        __builtin_amdgcn_wave_barrier();
        float acc2 = b4v;
#pragma unroll
        for (int j4 = 0; j4 < EMBED / 4; ++j4) {
            const float4 sv = s4[j4];
            acc2 = fmaf(sv.x, w4c[4 * j4 + 0], acc2);
            acc2 = fmaf(sv.y, w4c[4 * j4 + 1], acc2);
            acc2 = fmaf(sv.z, w4c[4 * j4 + 2], acc2);
            acc2 = fmaf(sv.w, w4c[4 * j4 + 3], acc2);
        }
        __builtin_amdgcn_wave_barrier();
        out[base] = x[base] + acc2;
    }
}

// ===========================================================================
extern "C" void kernel_launch(void* const* d_in, const int* in_sizes, int n_in,
                              void* d_out, int out_size, void* d_ws, size_t ws_size,
                              hipStream_t stream) {
    const float* x      = (const float*)d_in[0];
    const float* rbf    = (const float*)d_in[2];
    const int*   ei     = (const int*)d_in[3];
    const float* W1 = (const float*)d_in[4];
    const float* b1 = (const float*)d_in[5];
    const float* W2 = (const float*)d_in[6];
    const float* b2 = (const float*)d_in[7];
    const float* W3 = (const float*)d_in[8];
    const float* b3 = (const float*)d_in[9];
    const float* W4 = (const float*)d_in[10];
    const float* b4 = (const float*)d_in[11];
    float* out = (float*)d_out;

    const int E  = (int)(in_sizes[3] / 2);
    const int nn = in_sizes[0] / EMBED;
    const int nscan = (nn + SCAN_TILE - 1) / SCAN_TILE;
    const int nsPad = (nscan + 63) & ~63;

    // ws layout (sorted path): smsg (E*128 B) | offsets (nn+1) | counts (nn) | bsums
    const size_t msgBytes = (size_t)E * 128;
    unsigned* smsg  = (unsigned*)d_ws;
    int* offsets    = (int*)((char*)d_ws + msgBytes);
    int* counts     = offsets + nn + 1;
    int* bsums      = counts + nn;
    const size_t neededSort = msgBytes + sizeof(int) * ((size_t)(nn + 1) + nn + nsPad);

    const int nfull = E / 256;
    const int rem   = E - nfull * 256;
    const unsigned egrid = (unsigned)((E + 255) / 256);

    if (ws_size >= neededSort) {
        // ---- CSR offsets ----
        hipMemsetAsync(counts, 0, sizeof(int) * nn, stream);
        k_hist<<<dim3(egrid), dim3(256), 0, stream>>>(ei, counts, E);
        k_scan1<<<dim3((unsigned)nscan), dim3(256), 0, stream>>>(counts, offsets, bsums, nn);
        k_scan2<<<dim3(1), dim3(64), 0, stream>>>(bsums, nscan);
        k_scan3<<<dim3((unsigned)nscan), dim3(256), 0, stream>>>(offsets, bsums, counts, nn, E);
        // ---- phase 1: edge MLP, sorted stores (cursor = zeroed counts) ----
        if (nfull)
            edge_kernel_sort<false><<<dim3(nfull), dim3(256), 0, stream>>>(
                rbf, ei, W1, b1, W2, b2, offsets, counts, smsg, 0, E);
        if (rem)
            edge_kernel_sort<true><<<dim3(1), dim3(256), 0, stream>>>(
                rbf, ei, W1, b1, W2, b2, offsets, counts, smsg, nfull * 256, E);
        // ---- phase 2: streaming segment-sum + node MLP ----
        seg_node_kernel<<<dim3(2048), dim3(256), 0, stream>>>(
            x, smsg, offsets, W3, b3, W4, b4, out, nn);
    } else if (ws_size >= (size_t)nn * EMBED * sizeof(__half)) {
        // ---- fallback: r12 pk-f16 atomic path (396 us validated) ----
        hipMemsetAsync(d_ws, 0, (size_t)nn * EMBED * sizeof(__half), stream);
        if (nfull)
            edge_kernel32<false, true><<<dim3(nfull), dim3(256), 0, stream>>>(
                rbf, ei, W1, b1, W2, b2, d_ws, 0, E);
        if (rem)
            edge_kernel32<true, true><<<dim3(1), dim3(256), 0, stream>>>(
                rbf, ei, W1, b1, W2, b2, d_ws, nfull * 256, E);
        node_kernel<true><<<dim3(2048), dim3(256), 0, stream>>>(
            x, d_ws, W3, b3, W4, b4, out, nn);
    } else {
        hipMemsetAsync(out, 0, (size_t)nn * EMBED * sizeof(float), stream);
        if (nfull)
            edge_kernel32<false, false><<<dim3(nfull), dim3(256), 0, stream>>>(
                rbf, ei, W1, b1, W2, b2, out, 0, E);
        if (rem)
            edge_kernel32<true, false><<<dim3(1), dim3(256), 0, stream>>>(
                rbf, ei, W1, b1, W2, b2, out, nfull * 256, E);
        node_kernel<false><<<dim3(2048), dim3(256), 0, stream>>>(
            x, out, W3, b3, W4, b4, out, nn);
    }
}

// Round 14
// 576.856 us; speedup vs baseline: 1.1124x; 1.1124x over previous
//
#include <hip/hip_runtime.h>
#include <hip/hip_fp16.h>
#include <hip/hip_bf16.h>

typedef __attribute__((ext_vector_type(8)))  short bf16x8;
typedef __attribute__((ext_vector_type(4)))  float f32x4;
typedef __attribute__((ext_vector_type(16))) float f32x16;

constexpr int EMBED = 64;
constexpr int RBF   = 16;
constexpr int SCAN_TILE = 1024;

__device__ __forceinline__ short f2bf(float f) {
    __hip_bfloat16 h = __float2bfloat16(f);   // RNE
    return *reinterpret_cast<short*>(&h);
}
__device__ __forceinline__ float bf2f(short s) {
    unsigned u = ((unsigned)(unsigned short)s) << 16;
    return __uint_as_float(u);
}
__device__ __forceinline__ unsigned pk_bf(float lo, float hi) {
    unsigned l = (unsigned short)f2bf(lo);
    unsigned h = (unsigned short)f2bf(hi);
    return l | (h << 16);
}
__device__ __forceinline__ unsigned pk_f16(float lo, float hi) {
    __half2 h = __halves2half2(__float2half_rn(lo), __float2half_rn(hi));
    return *reinterpret_cast<unsigned*>(&h);
}
__device__ __forceinline__ void atom_pk_add_f16(__half* addr, unsigned data) {
    asm volatile("global_atomic_pk_add_f16 %0, %1, off"
                 :: "v"(addr), "v"(data) : "memory");
}
__device__ __forceinline__ float silu(float x) {
    return x * __builtin_amdgcn_rcpf(1.0f + __expf(-x));
}

// bf16(pi), bf16(pi/2) (r10-validated angle constants)
constexpr float PI_BF  = 3.140625f;
constexpr float PI2_BF = 1.5703125f;

// C/D row map for 32x32 MFMA (r12-validated)
__device__ __forceinline__ int crow(int j, int h) {
    return (j & 3) + 8 * (j >> 2) + 4 * h;
}

// ======================= CSR construction (r6/r13-validated) ===============
__global__ __launch_bounds__(256) void k_hist(
    const int* __restrict__ ei, int* __restrict__ counts, int E)
{
    int i = blockIdx.x * 256 + threadIdx.x;
    if (i < E) atomicAdd(&counts[ei[i]], 1);
}

__global__ __launch_bounds__(256) void k_scan1(
    const int* __restrict__ counts, int* __restrict__ offsets,
    int* __restrict__ bsums, int nn)
{
    __shared__ int lds[256];
    const int t = threadIdx.x;
    const int base = blockIdx.x * SCAN_TILE;
    int v[4]; int s = 0;
#pragma unroll
    for (int j = 0; j < 4; ++j) {
        const int i = base + t * 4 + j;
        v[j] = (i < nn) ? counts[i] : 0;
        s += v[j];
    }
    lds[t] = s;
    __syncthreads();
    for (int off = 1; off < 256; off <<= 1) {
        int x = (t >= off) ? lds[t - off] : 0;
        __syncthreads();
        lds[t] += x;
        __syncthreads();
    }
    int run = lds[t] - s;
    if (t == 255) bsums[blockIdx.x] = lds[255];
#pragma unroll
    for (int j = 0; j < 4; ++j) {
        const int i = base + t * 4 + j;
        if (i < nn) offsets[i] = run;
        run += v[j];
    }
}

__global__ void k_scan2(int* __restrict__ bsums, int nblk)
{
    if (threadIdx.x == 0 && blockIdx.x == 0) {
        int a = 0;
        for (int i = 0; i < nblk; ++i) { int t = bsums[i]; bsums[i] = a; a += t; }
    }
}

__global__ __launch_bounds__(256) void k_scan3(
    int* __restrict__ offsets, const int* __restrict__ bsums,
    int* __restrict__ counts, int nn, int Etot)
{
    const int base = blockIdx.x * SCAN_TILE;
    const int add = bsums[blockIdx.x];
#pragma unroll
    for (int j = 0; j < 4; ++j) {
        const int i = base + threadIdx.x * 4 + j;
        if (i < nn) { offsets[i] += add; counts[i] = 0; }   // counts -> cursor
    }
    if (blockIdx.x == 0 && threadIdx.x == 0) offsets[nn] = Etot;
}

// ======================= phase 1: GEMM1 + SiLU + sorted stores =============
// W2 commuted past the segment-sum: only silu(h1) leaves the edge kernel.
// 2 MFMA per 32 edges, no LDS msg tile, no GEMM2, no fp atomics.
template <bool GUARD>
__global__ __launch_bounds__(256) void edge1_lite(
    const float* __restrict__ rbf,
    const int* __restrict__ ei,
    const float* __restrict__ W1,
    const float* __restrict__ b1,
    const int* __restrict__ offsets,
    int* __restrict__ cursor,
    unsigned* __restrict__ smsg,   // E rows x 32 dwords (64 f16 ch each)
    int e_base, int E)
{
    __shared__ int lds_slot[256];
    __shared__ unsigned char lds_flag[256];
    __shared__ int wave_any[4];

    const int tid  = threadIdx.x;
    const int lane = tid & 63;
    const int wave = tid >> 6;
    const int n = lane & 31;
    const int h = lane >> 5;
    const int blk_e0 = e_base + blockIdx.x * 256;

    // ---- prologue: sorted slot + self-loop flag ----
    {
        const int e = blk_e0 + tid;
        const bool v = !GUARD || (e < E);
        int row = 0, col = 1;
        if (v) { row = ei[e]; col = ei[E + e]; }
        int slot = 0;
        if (v) slot = offsets[row] + atomicAdd(&cursor[row], 1);
        lds_slot[tid] = slot;
        const bool fl = v && (row == col);
        lds_flag[tid] = fl;
        const unsigned long long m = __ballot(fl);
        if (lane == 0) wave_any[wave] = (m != 0ull);
    }
    __syncthreads();

    // ---- GEMM1 B fragments + folded biases (r12-validated) ----
    bf16x8 b1f[2];
    float  b1v[2], dlt[2];
#pragma unroll
    for (int hh = 0; hh < 2; ++hh) {
        const int ch = 2 * n + hh;
#pragma unroll
        for (int j = 0; j < 8; ++j)
            b1f[hh][j] = f2bf(W1[(h * 8 + j) * EMBED + ch]);
        const float w16 = bf2f(f2bf(W1[RBF * EMBED + ch]));
        b1v[hh] = b1[ch] + PI_BF * w16;          // angle==pi folded into bias
        dlt[hh] = (PI2_BF - PI_BF) * w16;        // self-loop correction
    }

#pragma unroll 1
    for (int mt = 0; mt < 2; ++mt) {
        const int e0  = blk_e0 + wave * 64 + mt * 32;
        if (GUARD && e0 >= E) break;
        const int el0 = wave * 64 + mt * 32;

        // ---- A1: edge m=n, k = h*8+j ----
        bf16x8 a1 = {};
        {
            const int ea = e0 + n;
            if (!GUARD || ea < E) {
                const float4 p0 = *reinterpret_cast<const float4*>(rbf + (long long)ea * RBF + h * 8);
                const float4 p1 = *reinterpret_cast<const float4*>(rbf + (long long)ea * RBF + h * 8 + 4);
                a1[0] = f2bf(p0.x); a1[1] = f2bf(p0.y); a1[2] = f2bf(p0.z); a1[3] = f2bf(p0.w);
                a1[4] = f2bf(p1.x); a1[5] = f2bf(p1.y); a1[6] = f2bf(p1.z); a1[7] = f2bf(p1.w);
            }
        }

        // ---- GEMM1 (2 MFMA), bias-initialized ----
        f32x16 accA, accB;
#pragma unroll
        for (int j = 0; j < 16; ++j) { accA[j] = b1v[0]; accB[j] = b1v[1]; }
        accA = __builtin_amdgcn_mfma_f32_32x32x16_bf16(a1, b1f[0], accA, 0, 0, 0);
        accB = __builtin_amdgcn_mfma_f32_32x32x16_bf16(a1, b1f[1], accB, 0, 0, 0);

        if (wave_any[wave]) {
#pragma unroll
            for (int j = 0; j < 16; ++j) {
                const int m = crow(j, h);
                if (lds_flag[el0 + m]) { accA[j] += dlt[0]; accB[j] += dlt[1]; }
            }
        }

        // ---- SiLU + pk-f16 sorted store (128-B coalesced per edge) ----
#pragma unroll
        for (int j = 0; j < 16; ++j) {
            const int m = crow(j, h);
            const int eat = e0 + m;
            if (!GUARD || eat < E) {
                const size_t slot = (size_t)lds_slot[el0 + m];
                smsg[slot * 32u + (unsigned)n] = pk_f16(silu(accA[j]), silu(accB[j]));
            }
        }
    }
}

// ======================= phase 2a: segment-sum + W2 (fp32) =================
// Wave per node: contiguous uint2 reads (4 rows/instr), fp32 sums,
// agg = ssum @ W2 + deg * b2. agg goes to d_out (node MLP runs in place).
__global__ __launch_bounds__(256) void k_agg2(
    const unsigned* __restrict__ smsg,
    const int* __restrict__ offsets,
    const float* __restrict__ W2, const float* __restrict__ b2,
    float* __restrict__ agg, int nn)
{
    __shared__ __align__(16) float lds_s[4][EMBED];
    const int lane = threadIdx.x & 63;
    const int wave = threadIdx.x >> 6;
    const int dw = lane & 15;    // dword-pair -> channels 4dw..4dw+3
    const int rp = lane >> 4;    // row offset 0..3

    float w2c[EMBED];
#pragma unroll
    for (int j = 0; j < EMBED; ++j) w2c[j] = W2[j * EMBED + lane];
    const float b2v = b2[lane];

    const int nid = blockIdx.x * 4 + wave;
    if (nid >= nn) return;

    const int beg = offsets[nid];
    const int end = offsets[nid + 1];

    float s0 = 0.f, s1 = 0.f, s2 = 0.f, s3 = 0.f;
    for (int j = beg + rp; j < end; j += 4) {
        const uint2 d = *reinterpret_cast<const uint2*>(smsg + (size_t)j * 32u + 2u * (unsigned)dw);
        const __half2 h0 = *reinterpret_cast<const __half2*>(&d.x);
        const __half2 h1 = *reinterpret_cast<const __half2*>(&d.y);
        s0 += __low2float(h0); s1 += __high2float(h0);
        s2 += __low2float(h1); s3 += __high2float(h1);
    }
    // reduce across the 4 row-parity groups (lane bits 4,5)
    s0 += __shfl_xor(s0, 16, 64); s1 += __shfl_xor(s1, 16, 64);
    s2 += __shfl_xor(s2, 16, 64); s3 += __shfl_xor(s3, 16, 64);
    s0 += __shfl_xor(s0, 32, 64); s1 += __shfl_xor(s1, 32, 64);
    s2 += __shfl_xor(s2, 32, 64); s3 += __shfl_xor(s3, 32, 64);

    if (lane < 16) {
        float4 v = {s0, s1, s2, s3};
        reinterpret_cast<float4*>(lds_s[wave])[dw] = v;
    }
    __builtin_amdgcn_wave_barrier();

    const float4* s4 = reinterpret_cast<const float4*>(lds_s[wave]);
    float acc = (float)(end - beg) * b2v;
#pragma unroll
    for (int j4 = 0; j4 < EMBED / 4; ++j4) {
        const float4 sv = s4[j4];
        acc = fmaf(sv.x, w2c[4 * j4 + 0], acc);
        acc = fmaf(sv.y, w2c[4 * j4 + 1], acc);
        acc = fmaf(sv.z, w2c[4 * j4 + 2], acc);
        acc = fmaf(sv.w, w2c[4 * j4 + 3], acc);
    }
    __builtin_amdgcn_wave_barrier();

    agg[(size_t)nid * EMBED + lane] = acc;
}

// ======================= node kernel (validated; in-place capable) =========
template <bool F16>
__global__ __launch_bounds__(256) void node_kernel(
    const float* __restrict__ x, const void* __restrict__ aggv,
    const float* __restrict__ W3, const float* __restrict__ b3,
    const float* __restrict__ W4, const float* __restrict__ b4,
    float* __restrict__ out, int nn)
{
    __shared__ __align__(16) float lds_s[4][EMBED];
    const int lane = threadIdx.x & 63;
    const int wave = threadIdx.x >> 6;
    float w3c[EMBED], w4c[EMBED];
#pragma unroll
    for (int j = 0; j < EMBED; ++j) w3c[j] = W3[j * EMBED + lane];
#pragma unroll
    for (int j = 0; j < EMBED; ++j) w4c[j] = W4[j * EMBED + lane];
    const float b3v = b3[lane];
    const float b4v = b4[lane];
    const float4* s4 = reinterpret_cast<const float4*>(lds_s[wave]);
    const int wid = blockIdx.x * 4 + wave;
    const int nw  = gridDim.x * 4;
    for (int n = wid; n < nn; n += nw) {
        const long long base = (long long)n * EMBED + lane;
        float a;
        if (F16) a = __half2float(reinterpret_cast<const __half*>(aggv)[base]);
        else     a = reinterpret_cast<const float*>(aggv)[base];
        lds_s[wave][lane] = a;
        __builtin_amdgcn_wave_barrier();
        float acc = b3v;
#pragma unroll
        for (int j4 = 0; j4 < EMBED / 4; ++j4) {
            const float4 sv = s4[j4];
            acc = fmaf(sv.x, w3c[4 * j4 + 0], acc);
            acc = fmaf(sv.y, w3c[4 * j4 + 1], acc);
            acc = fmaf(sv.z, w3c[4 * j4 + 2], acc);
            acc = fmaf(sv.w, w3c[4 * j4 + 3], acc);
        }
        const float s = acc * __builtin_amdgcn_rcpf(1.0f + __expf(-acc));
        __builtin_amdgcn_wave_barrier();
        lds_s[wave][lane] = s;
        __builtin_amdgcn_wave_barrier();
        float acc2 = b4v;
#pragma unroll
        for (int j4 = 0; j4 < EMBED / 4; ++j4) {
            const float4 sv = s4[j4];
            acc2 = fmaf(sv.x, w4c[4 * j4 + 0], acc2);
            acc2 = fmaf(sv.y, w4c[4 * j4 + 1], acc2);
            acc2 = fmaf(sv.z, w4c[4 * j4 + 2], acc2);
            acc2 = fmaf(sv.w, w4c[4 * j4 + 3], acc2);
        }
        __builtin_amdgcn_wave_barrier();
        out[base] = x[base] + acc2;
    }
}

// ======================= fallback: r12 atomic path (396 us validated) ======
template <bool GUARD, bool F16>
__global__ __launch_bounds__(256, 2) void edge_kernel32(
    const float* __restrict__ rbf, const int* __restrict__ ei,
    const float* __restrict__ W1, const float* __restrict__ b1,
    const float* __restrict__ W2, const float* __restrict__ b2,
    void* __restrict__ agg, int e_base, int E)
{
    __shared__ __align__(16) short lds_s[4][32 * 64];
    __shared__ int lds_row[256];
    __shared__ unsigned char lds_flag[256];
    __shared__ int wave_any[4];
    const int tid = threadIdx.x, lane = tid & 63, wave = tid >> 6;
    const int n = lane & 31, h = lane >> 5;
    const int blk_e0 = e_base + blockIdx.x * 256;
    {
        const int e = blk_e0 + tid;
        const bool v = !GUARD || (e < E);
        const int row = v ? ei[e] : 0;
        const int col = v ? ei[E + e] : 1;
        lds_row[tid] = row;
        const bool fl = v && (row == col);
        lds_flag[tid] = fl;
        const unsigned long long m = __ballot(fl);
        if (lane == 0) wave_any[wave] = (m != 0ull);
    }
    __syncthreads();
    bf16x8 b1f[2];
    float b1v[2], dlt[2], b2v[2];
#pragma unroll
    for (int hh = 0; hh < 2; ++hh) {
        const int ch = 2 * n + hh;
#pragma unroll
        for (int j = 0; j < 8; ++j)
            b1f[hh][j] = f2bf(W1[(h * 8 + j) * EMBED + ch]);
        const float w16 = bf2f(f2bf(W1[RBF * EMBED + ch]));
        b1v[hh] = b1[ch] + PI_BF * w16;
        dlt[hh] = (PI2_BF - PI_BF) * w16;
        b2v[hh] = b2[ch];
    }
    bf16x8 b2f[4][2];
#pragma unroll
    for (int kk = 0; kk < 4; ++kk)
#pragma unroll
        for (int hh = 0; hh < 2; ++hh) {
            const int ch = 2 * n + hh;
#pragma unroll
            for (int j = 0; j < 8; ++j)
                b2f[kk][hh][j] = f2bf(W2[(kk * 16 + h * 8 + j) * EMBED + ch]);
        }
    char* const sl = reinterpret_cast<char*>(lds_s[wave]);
#pragma unroll 1
    for (int mt = 0; mt < 2; ++mt) {
        const int e0 = blk_e0 + wave * 64 + mt * 32;
        if (GUARD && e0 >= E) break;
        const int el0 = wave * 64 + mt * 32;
        bf16x8 a1 = {};
        {
            const int ea = e0 + n;
            if (!GUARD || ea < E) {
                const float4 p0 = *reinterpret_cast<const float4*>(rbf + (long long)ea * RBF + h * 8);
                const float4 p1 = *reinterpret_cast<const float4*>(rbf + (long long)ea * RBF + h * 8 + 4);
                a1[0] = f2bf(p0.x); a1[1] = f2bf(p0.y); a1[2] = f2bf(p0.z); a1[3] = f2bf(p0.w);
                a1[4] = f2bf(p1.x); a1[5] = f2bf(p1.y); a1[6] = f2bf(p1.z); a1[7] = f2bf(p1.w);
            }
        }
        f32x16 accA, accB;
#pragma unroll
        for (int j = 0; j < 16; ++j) { accA[j] = b1v[0]; accB[j] = b1v[1]; }
        accA = __builtin_amdgcn_mfma_f32_32x32x16_bf16(a1, b1f[0], accA, 0, 0, 0);
        accB = __builtin_amdgcn_mfma_f32_32x32x16_bf16(a1, b1f[1], accB, 0, 0, 0);
        if (wave_any[wave]) {
#pragma unroll
            for (int j = 0; j < 16; ++j) {
                const int m = crow(j, h);
                if (lds_flag[el0 + m]) { accA[j] += dlt[0]; accB[j] += dlt[1]; }
            }
        }
#pragma unroll
        for (int j = 0; j < 16; ++j) {
            const int m = crow(j, h);
            const unsigned u = pk_bf(silu(accA[j]), silu(accB[j]));
            *reinterpret_cast<unsigned*>(sl + m * 128 + ((4 * n) ^ ((m & 7) << 4))) = u;
        }
        __builtin_amdgcn_wave_barrier();
        f32x16 acc2A, acc2B;
#pragma unroll
        for (int j = 0; j < 16; ++j) { acc2A[j] = b2v[0]; acc2B[j] = b2v[1]; }
#pragma unroll
        for (int kk = 0; kk < 4; ++kk) {
            const int byte = n * 128 + ((kk * 32 + h * 16) ^ ((n & 7) << 4));
            const bf16x8 a2 = *reinterpret_cast<const bf16x8*>(sl + byte);
            acc2A = __builtin_amdgcn_mfma_f32_32x32x16_bf16(a2, b2f[kk][0], acc2A, 0, 0, 0);
            acc2B = __builtin_amdgcn_mfma_f32_32x32x16_bf16(a2, b2f[kk][1], acc2B, 0, 0, 0);
        }
        __builtin_amdgcn_wave_barrier();
#pragma unroll
        for (int j = 0; j < 16; ++j) {
            const int m = crow(j, h);
            const int eat = e0 + m;
            if (!GUARD || eat < E) {
                const unsigned row = (unsigned)lds_row[el0 + m];
                if (F16) {
                    __half* const dst = reinterpret_cast<__half*>(agg) + row * 64u;
                    atom_pk_add_f16(dst + 2 * n, pk_f16(acc2A[j], acc2B[j]));
                } else {
                    float* const dst = reinterpret_cast<float*>(agg) + row * 64u;
                    atomicAdd(dst + 2 * n,     acc2A[j]);
                    atomicAdd(dst + 2 * n + 1, acc2B[j]);
                }
            }
        }
    }
}

// ===========================================================================
extern "C" void kernel_launch(void* const* d_in, const int* in_sizes, int n_in,
                              void* d_out, int out_size, void* d_ws, size_t ws_size,
                              hipStream_t stream) {
    const float* x      = (const float*)d_in[0];
    const float* rbf    = (const float*)d_in[2];
    const int*   ei     = (const int*)d_in[3];
    const float* W1 = (const float*)d_in[4];
    const float* b1 = (const float*)d_in[5];
    const float* W2 = (const float*)d_in[6];
    const float* b2 = (const float*)d_in[7];
    const float* W3 = (const float*)d_in[8];
    const float* b3 = (const float*)d_in[9];
    const float* W4 = (const float*)d_in[10];
    const float* b4 = (const float*)d_in[11];
    float* out = (float*)d_out;

    const int E  = (int)(in_sizes[3] / 2);
    const int nn = in_sizes[0] / EMBED;
    const int nscan = (nn + SCAN_TILE - 1) / SCAN_TILE;
    const int nsPad = (nscan + 63) & ~63;

    // ws layout: smsg (E*128 B) | offsets (nn+1) | counts (nn) | bsums
    const size_t msgBytes = (size_t)E * 128;
    unsigned* smsg  = (unsigned*)d_ws;
    int* offsets    = (int*)((char*)d_ws + msgBytes);
    int* counts     = offsets + nn + 1;
    int* bsums      = counts + nn;
    const size_t neededSort = msgBytes + sizeof(int) * ((size_t)(nn + 1) + nn + nsPad);

    const int nfull = E / 256;
    const int rem   = E - nfull * 256;
    const unsigned egrid = (unsigned)((E + 255) / 256);

    if (ws_size >= neededSort) {
        // ---- CSR offsets ----
        hipMemsetAsync(counts, 0, sizeof(int) * nn, stream);
        k_hist<<<dim3(egrid), dim3(256), 0, stream>>>(ei, counts, E);
        k_scan1<<<dim3((unsigned)nscan), dim3(256), 0, stream>>>(counts, offsets, bsums, nn);
        k_scan2<<<dim3(1), dim3(64), 0, stream>>>(bsums, nscan);
        k_scan3<<<dim3((unsigned)nscan), dim3(256), 0, stream>>>(offsets, bsums, counts, nn, E);
        // ---- phase 1: GEMM1 + SiLU, sorted stores (cursor = zeroed counts) ----
        if (nfull)
            edge1_lite<false><<<dim3(nfull), dim3(256), 0, stream>>>(
                rbf, ei, W1, b1, offsets, counts, smsg, 0, E);
        if (rem)
            edge1_lite<true><<<dim3(1), dim3(256), 0, stream>>>(
                rbf, ei, W1, b1, offsets, counts, smsg, nfull * 256, E);
        // ---- phase 2a: streaming segment-sum + W2 -> agg in d_out ----
        k_agg2<<<dim3((unsigned)((nn + 3) / 4)), dim3(256), 0, stream>>>(
            smsg, offsets, W2, b2, out, nn);
        // ---- phase 2b: node MLP in place ----
        node_kernel<false><<<dim3(2048), dim3(256), 0, stream>>>(
            x, out, W3, b3, W4, b4, out, nn);
    } else if (ws_size >= (size_t)nn * EMBED * sizeof(__half)) {
        // ---- fallback: r12 pk-f16 atomic path (396 us validated) ----
        hipMemsetAsync(d_ws, 0, (size_t)nn * EMBED * sizeof(__half), stream);
        if (nfull)
            edge_kernel32<false, true><<<dim3(nfull), dim3(256), 0, stream>>>(
                rbf, ei, W1, b1, W2, b2, d_ws, 0, E);
        if (rem)
            edge_kernel32<true, true><<<dim3(1), dim3(256), 0, stream>>>(
                rbf, ei, W1, b1, W2, b2, d_ws, nfull * 256, E);
        node_kernel<true><<<dim3(2048), dim3(256), 0, stream>>>(
            x, d_ws, W3, b3, W4, b4, out, nn);
    } else {
        hipMemsetAsync(out, 0, (size_t)nn * EMBED * sizeof(float), stream);
        if (nfull)
            edge_kernel32<false, false><<<dim3(nfull), dim3(256), 0, stream>>>(
                rbf, ei, W1, b1, W2, b2, out, 0, E);
        if (rem)
            edge_kernel32<true, false><<<dim3(1), dim3(256), 0, stream>>>(
                rbf, ei, W1, b1, W2, b2, out, nfull * 256, E);
        node_kernel<false><<<dim3(2048), dim3(256), 0, stream>>>(
            x, out, W3, b3, W4, b4, out, nn);
    }
}

// Round 15
// 569.963 us; speedup vs baseline: 1.1259x; 1.0121x over previous
//
#include <hip/hip_runtime.h>
#include <hip/hip_fp16.h>
#include <hip/hip_bf16.h>

typedef __attribute__((ext_vector_type(8)))  short bf16x8;
typedef __attribute__((ext_vector_type(4)))  float f32x4;
typedef __attribute__((ext_vector_type(16))) float f32x16;

constexpr int EMBED = 64;
constexpr int RBF   = 16;
constexpr int SCAN_TILE = 1024;

__device__ __forceinline__ short f2bf(float f) {
    __hip_bfloat16 h = __float2bfloat16(f);   // RNE
    return *reinterpret_cast<short*>(&h);
}
__device__ __forceinline__ float bf2f(short s) {
    unsigned u = ((unsigned)(unsigned short)s) << 16;
    return __uint_as_float(u);
}
__device__ __forceinline__ unsigned pk_bf(float lo, float hi) {
    unsigned l = (unsigned short)f2bf(lo);
    unsigned h = (unsigned short)f2bf(hi);
    return l | (h << 16);
}
__device__ __forceinline__ unsigned pk_f16(float lo, float hi) {
    __half2 h = __halves2half2(__float2half_rn(lo), __float2half_rn(hi));
    return *reinterpret_cast<unsigned*>(&h);
}
__device__ __forceinline__ void atom_pk_add_f16(__half* addr, unsigned data) {
    asm volatile("global_atomic_pk_add_f16 %0, %1, off"
                 :: "v"(addr), "v"(data) : "memory");
}
__device__ __forceinline__ float silu(float x) {
    return x * __builtin_amdgcn_rcpf(1.0f + __expf(-x));
}

// bf16(pi), bf16(pi/2) (r10-validated angle constants)
constexpr float PI_BF  = 3.140625f;
constexpr float PI2_BF = 1.5703125f;

// C/D row map for 32x32 MFMA (r12-validated)
__device__ __forceinline__ int crow(int j, int h) {
    return (j & 3) + 8 * (j >> 2) + 4 * h;
}

// ======================= CSR construction ==================================
__global__ __launch_bounds__(256) void k_hist(
    const int* __restrict__ ei, int* __restrict__ counts, int E)
{
    int i = blockIdx.x * 256 + threadIdx.x;
    if (i < E) atomicAdd(&counts[ei[i]], 1);
}

__global__ __launch_bounds__(256) void k_scan1(
    const int* __restrict__ counts, int* __restrict__ offsets,
    int* __restrict__ bsums, int nn)
{
    __shared__ int lds[256];
    const int t = threadIdx.x;
    const int base = blockIdx.x * SCAN_TILE;
    int v[4]; int s = 0;
#pragma unroll
    for (int j = 0; j < 4; ++j) {
        const int i = base + t * 4 + j;
        v[j] = (i < nn) ? counts[i] : 0;
        s += v[j];
    }
    lds[t] = s;
    __syncthreads();
    for (int off = 1; off < 256; off <<= 1) {
        int x = (t >= off) ? lds[t - off] : 0;
        __syncthreads();
        lds[t] += x;
        __syncthreads();
    }
    int run = lds[t] - s;
    if (t == 255) bsums[blockIdx.x] = lds[255];
#pragma unroll
    for (int j = 0; j < 4; ++j) {
        const int i = base + t * 4 + j;
        if (i < nn) offsets[i] = run;
        run += v[j];
    }
}

// parallel exclusive scan of block sums (nblk <= 256 for nn <= 262144;
// serial fallback otherwise). Replaces the serial single-thread loop
// (98 dependent HBM round-trips ~ 40-70 us).
__global__ __launch_bounds__(256) void k_scan2(int* __restrict__ bsums, int nblk)
{
    __shared__ int lds[256];
    const int t = threadIdx.x;
    if (nblk <= 256) {
        const int v = (t < nblk) ? bsums[t] : 0;
        lds[t] = v;
        __syncthreads();
        for (int off = 1; off < 256; off <<= 1) {
            int x = (t >= off) ? lds[t - off] : 0;
            __syncthreads();
            lds[t] += x;
            __syncthreads();
        }
        if (t < nblk) bsums[t] = lds[t] - v;   // exclusive prefix
    } else if (t == 0) {
        int a = 0;
        for (int i = 0; i < nblk; ++i) { int tv = bsums[i]; bsums[i] = a; a += tv; }
    }
}

__global__ __launch_bounds__(256) void k_scan3(
    int* __restrict__ offsets, const int* __restrict__ bsums,
    int* __restrict__ counts, int nn, int Etot)
{
    const int base = blockIdx.x * SCAN_TILE;
    const int add = bsums[blockIdx.x];
#pragma unroll
    for (int j = 0; j < 4; ++j) {
        const int i = base + threadIdx.x * 4 + j;
        if (i < nn) { offsets[i] += add; counts[i] = 0; }   // counts -> cursor
    }
    if (blockIdx.x == 0 && threadIdx.x == 0) offsets[nn] = Etot;
}

// ======================= phase 1: GEMM1 + SiLU + sorted stores =============
// (r14-validated structure; smsg stores now nontemporal)
template <bool GUARD>
__global__ __launch_bounds__(256) void edge1_lite(
    const float* __restrict__ rbf,
    const int* __restrict__ ei,
    const float* __restrict__ W1,
    const float* __restrict__ b1,
    const int* __restrict__ offsets,
    int* __restrict__ cursor,
    unsigned* __restrict__ smsg,   // E rows x 32 dwords (64 f16 ch each)
    int e_base, int E)
{
    __shared__ int lds_slot[256];
    __shared__ unsigned char lds_flag[256];
    __shared__ int wave_any[4];

    const int tid  = threadIdx.x;
    const int lane = tid & 63;
    const int wave = tid >> 6;
    const int n = lane & 31;
    const int h = lane >> 5;
    const int blk_e0 = e_base + blockIdx.x * 256;

    {
        const int e = blk_e0 + tid;
        const bool v = !GUARD || (e < E);
        int row = 0, col = 1;
        if (v) { row = ei[e]; col = ei[E + e]; }
        int slot = 0;
        if (v) slot = offsets[row] + atomicAdd(&cursor[row], 1);
        lds_slot[tid] = slot;
        const bool fl = v && (row == col);
        lds_flag[tid] = fl;
        const unsigned long long m = __ballot(fl);
        if (lane == 0) wave_any[wave] = (m != 0ull);
    }
    __syncthreads();

    bf16x8 b1f[2];
    float  b1v[2], dlt[2];
#pragma unroll
    for (int hh = 0; hh < 2; ++hh) {
        const int ch = 2 * n + hh;
#pragma unroll
        for (int j = 0; j < 8; ++j)
            b1f[hh][j] = f2bf(W1[(h * 8 + j) * EMBED + ch]);
        const float w16 = bf2f(f2bf(W1[RBF * EMBED + ch]));
        b1v[hh] = b1[ch] + PI_BF * w16;          // angle==pi folded into bias
        dlt[hh] = (PI2_BF - PI_BF) * w16;        // self-loop correction
    }

#pragma unroll 1
    for (int mt = 0; mt < 2; ++mt) {
        const int e0  = blk_e0 + wave * 64 + mt * 32;
        if (GUARD && e0 >= E) break;
        const int el0 = wave * 64 + mt * 32;

        bf16x8 a1 = {};
        {
            const int ea = e0 + n;
            if (!GUARD || ea < E) {
                const float4 p0 = *reinterpret_cast<const float4*>(rbf + (long long)ea * RBF + h * 8);
                const float4 p1 = *reinterpret_cast<const float4*>(rbf + (long long)ea * RBF + h * 8 + 4);
                a1[0] = f2bf(p0.x); a1[1] = f2bf(p0.y); a1[2] = f2bf(p0.z); a1[3] = f2bf(p0.w);
                a1[4] = f2bf(p1.x); a1[5] = f2bf(p1.y); a1[6] = f2bf(p1.z); a1[7] = f2bf(p1.w);
            }
        }

        f32x16 accA, accB;
#pragma unroll
        for (int j = 0; j < 16; ++j) { accA[j] = b1v[0]; accB[j] = b1v[1]; }
        accA = __builtin_amdgcn_mfma_f32_32x32x16_bf16(a1, b1f[0], accA, 0, 0, 0);
        accB = __builtin_amdgcn_mfma_f32_32x32x16_bf16(a1, b1f[1], accB, 0, 0, 0);

        if (wave_any[wave]) {
#pragma unroll
            for (int j = 0; j < 16; ++j) {
                const int m = crow(j, h);
                if (lds_flag[el0 + m]) { accA[j] += dlt[0]; accB[j] += dlt[1]; }
            }
        }

#pragma unroll
        for (int j = 0; j < 16; ++j) {
            const int m = crow(j, h);
            const int eat = e0 + m;
            if (!GUARD || eat < E) {
                const size_t slot = (size_t)lds_slot[el0 + m];
                __builtin_nontemporal_store(
                    pk_f16(silu(accA[j]), silu(accB[j])),
                    smsg + slot * 32u + (unsigned)n);
            }
        }
    }
}

// ======================= phase 2a: segment-sum + W2 (fp32) =================
// Grid-strided wave-per-node (amortizes the W2 column load over ~12 nodes);
// nontemporal streaming reads of smsg.
__global__ __launch_bounds__(256) void k_agg2(
    const unsigned* __restrict__ smsg,
    const int* __restrict__ offsets,
    const float* __restrict__ W2, const float* __restrict__ b2,
    float* __restrict__ agg, int nn)
{
    __shared__ __align__(16) float lds_s[4][EMBED];
    const int lane = threadIdx.x & 63;
    const int wave = threadIdx.x >> 6;
    const int dw = lane & 15;    // dword-pair -> channels 4dw..4dw+3
    const int rp = lane >> 4;    // row offset 0..3

    float w2c[EMBED];
#pragma unroll
    for (int j = 0; j < EMBED; ++j) w2c[j] = W2[j * EMBED + lane];
    const float b2v = b2[lane];

    const float4* s4 = reinterpret_cast<const float4*>(lds_s[wave]);
    const int wid = blockIdx.x * 4 + wave;
    const int nw  = gridDim.x * 4;

    for (int nid = wid; nid < nn; nid += nw) {
        const int beg = offsets[nid];
        const int end = offsets[nid + 1];

        float s0 = 0.f, s1 = 0.f, s2 = 0.f, s3 = 0.f;
        for (int j = beg + rp; j < end; j += 4) {
            const unsigned long long d = __builtin_nontemporal_load(
                reinterpret_cast<const unsigned long long*>(
                    smsg + (size_t)j * 32u + 2u * (unsigned)dw));
            const unsigned lo = (unsigned)d;
            const unsigned hi = (unsigned)(d >> 32);
            const __half2 h0 = *reinterpret_cast<const __half2*>(&lo);
            const __half2 h1 = *reinterpret_cast<const __half2*>(&hi);
            s0 += __low2float(h0); s1 += __high2float(h0);
            s2 += __low2float(h1); s3 += __high2float(h1);
        }
        s0 += __shfl_xor(s0, 16, 64); s1 += __shfl_xor(s1, 16, 64);
        s2 += __shfl_xor(s2, 16, 64); s3 += __shfl_xor(s3, 16, 64);
        s0 += __shfl_xor(s0, 32, 64); s1 += __shfl_xor(s1, 32, 64);
        s2 += __shfl_xor(s2, 32, 64); s3 += __shfl_xor(s3, 32, 64);

        if (lane < 16) {
            float4 v = {s0, s1, s2, s3};
            reinterpret_cast<float4*>(lds_s[wave])[dw] = v;
        }
        __builtin_amdgcn_wave_barrier();

        float acc = (float)(end - beg) * b2v;
#pragma unroll
        for (int j4 = 0; j4 < EMBED / 4; ++j4) {
            const float4 sv = s4[j4];
            acc = fmaf(sv.x, w2c[4 * j4 + 0], acc);
            acc = fmaf(sv.y, w2c[4 * j4 + 1], acc);
            acc = fmaf(sv.z, w2c[4 * j4 + 2], acc);
            acc = fmaf(sv.w, w2c[4 * j4 + 3], acc);
        }
        __builtin_amdgcn_wave_barrier();

        agg[(size_t)nid * EMBED + lane] = acc;
    }
}

// ======================= node kernel (validated; in-place capable) =========
template <bool F16>
__global__ __launch_bounds__(256) void node_kernel(
    const float* __restrict__ x, const void* __restrict__ aggv,
    const float* __restrict__ W3, const float* __restrict__ b3,
    const float* __restrict__ W4, const float* __restrict__ b4,
    float* __restrict__ out, int nn)
{
    __shared__ __align__(16) float lds_s[4][EMBED];
    const int lane = threadIdx.x & 63;
    const int wave = threadIdx.x >> 6;
    float w3c[EMBED], w4c[EMBED];
#pragma unroll
    for (int j = 0; j < EMBED; ++j) w3c[j] = W3[j * EMBED + lane];
#pragma unroll
    for (int j = 0; j < EMBED; ++j) w4c[j] = W4[j * EMBED + lane];
    const float b3v = b3[lane];
    const float b4v = b4[lane];
    const float4* s4 = reinterpret_cast<const float4*>(lds_s[wave]);
    const int wid = blockIdx.x * 4 + wave;
    const int nw  = gridDim.x * 4;
    for (int n = wid; n < nn; n += nw) {
        const long long base = (long long)n * EMBED + lane;
        float a;
        if (F16) a = __half2float(reinterpret_cast<const __half*>(aggv)[base]);
        else     a = reinterpret_cast<const float*>(aggv)[base];
        lds_s[wave][lane] = a;
        __builtin_amdgcn_wave_barrier();
        float acc = b3v;
#pragma unroll
        for (int j4 = 0; j4 < EMBED / 4; ++j4) {
            const float4 sv = s4[j4];
            acc = fmaf(sv.x, w3c[4 * j4 + 0], acc);
            acc = fmaf(sv.y, w3c[4 * j4 + 1], acc);
            acc = fmaf(sv.z, w3c[4 * j4 + 2], acc);
            acc = fmaf(sv.w, w3c[4 * j4 + 3], acc);
        }
        const float s = acc * __builtin_amdgcn_rcpf(1.0f + __expf(-acc));
        __builtin_amdgcn_wave_barrier();
        lds_s[wave][lane] = s;
        __builtin_amdgcn_wave_barrier();
        float acc2 = b4v;
#pragma unroll
        for (int j4 = 0; j4 < EMBED / 4; ++j4) {
            const float4 sv = s4[j4];
            acc2 = fmaf(sv.x, w4c[4 * j4 + 0], acc2);
            acc2 = fmaf(sv.y, w4c[4 * j4 + 1], acc2);
            acc2 = fmaf(sv.z, w4c[4 * j4 + 2], acc2);
            acc2 = fmaf(sv.w, w4c[4 * j4 + 3], acc2);
        }
        __builtin_amdgcn_wave_barrier();
        out[base] = x[base] + acc2;
    }
}

// ======================= fallback: r12 atomic path (396 us validated) ======
template <bool GUARD, bool F16>
__global__ __launch_bounds__(256, 2) void edge_kernel32(
    const float* __restrict__ rbf, const int* __restrict__ ei,
    const float* __restrict__ W1, const float* __restrict__ b1,
    const float* __restrict__ W2, const float* __restrict__ b2,
    void* __restrict__ agg, int e_base, int E)
{
    __shared__ __align__(16) short lds_s[4][32 * 64];
    __shared__ int lds_row[256];
    __shared__ unsigned char lds_flag[256];
    __shared__ int wave_any[4];
    const int tid = threadIdx.x, lane = tid & 63, wave = tid >> 6;
    const int n = lane & 31, h = lane >> 5;
    const int blk_e0 = e_base + blockIdx.x * 256;
    {
        const int e = blk_e0 + tid;
        const bool v = !GUARD || (e < E);
        const int row = v ? ei[e] : 0;
        const int col = v ? ei[E + e] : 1;
        lds_row[tid] = row;
        const bool fl = v && (row == col);
        lds_flag[tid] = fl;
        const unsigned long long m = __ballot(fl);
        if (lane == 0) wave_any[wave] = (m != 0ull);
    }
    __syncthreads();
    bf16x8 b1f[2];
    float b1v[2], dlt[2], b2v[2];
#pragma unroll
    for (int hh = 0; hh < 2; ++hh) {
        const int ch = 2 * n + hh;
#pragma unroll
        for (int j = 0; j < 8; ++j)
            b1f[hh][j] = f2bf(W1[(h * 8 + j) * EMBED + ch]);
        const float w16 = bf2f(f2bf(W1[RBF * EMBED + ch]));
        b1v[hh] = b1[ch] + PI_BF * w16;
        dlt[hh] = (PI2_BF - PI_BF) * w16;
        b2v[hh] = b2[ch];
    }
    bf16x8 b2f[4][2];
#pragma unroll
    for (int kk = 0; kk < 4; ++kk)
#pragma unroll
        for (int hh = 0; hh < 2; ++hh) {
            const int ch = 2 * n + hh;
#pragma unroll
            for (int j = 0; j < 8; ++j)
                b2f[kk][hh][j] = f2bf(W2[(kk * 16 + h * 8 + j) * EMBED + ch]);
        }
    char* const sl = reinterpret_cast<char*>(lds_s[wave]);
#pragma unroll 1
    for (int mt = 0; mt < 2; ++mt) {
        const int e0 = blk_e0 + wave * 64 + mt * 32;
        if (GUARD && e0 >= E) break;
        const int el0 = wave * 64 + mt * 32;
        bf16x8 a1 = {};
        {
            const int ea = e0 + n;
            if (!GUARD || ea < E) {
                const float4 p0 = *reinterpret_cast<const float4*>(rbf + (long long)ea * RBF + h * 8);
                const float4 p1 = *reinterpret_cast<const float4*>(rbf + (long long)ea * RBF + h * 8 + 4);
                a1[0] = f2bf(p0.x); a1[1] = f2bf(p0.y); a1[2] = f2bf(p0.z); a1[3] = f2bf(p0.w);
                a1[4] = f2bf(p1.x); a1[5] = f2bf(p1.y); a1[6] = f2bf(p1.z); a1[7] = f2bf(p1.w);
            }
        }
        f32x16 accA, accB;
#pragma unroll
        for (int j = 0; j < 16; ++j) { accA[j] = b1v[0]; accB[j] = b1v[1]; }
        accA = __builtin_amdgcn_mfma_f32_32x32x16_bf16(a1, b1f[0], accA, 0, 0, 0);
        accB = __builtin_amdgcn_mfma_f32_32x32x16_bf16(a1, b1f[1], accB, 0, 0, 0);
        if (wave_any[wave]) {
#pragma unroll
            for (int j = 0; j < 16; ++j) {
                const int m = crow(j, h);
                if (lds_flag[el0 + m]) { accA[j] += dlt[0]; accB[j] += dlt[1]; }
            }
        }
#pragma unroll
        for (int j = 0; j < 16; ++j) {
            const int m = crow(j, h);
            const unsigned u = pk_bf(silu(accA[j]), silu(accB[j]));
            *reinterpret_cast<unsigned*>(sl + m * 128 + ((4 * n) ^ ((m & 7) << 4))) = u;
        }
        __builtin_amdgcn_wave_barrier();
        f32x16 acc2A, acc2B;
#pragma unroll
        for (int j = 0; j < 16; ++j) { acc2A[j] = b2v[0]; acc2B[j] = b2v[1]; }
#pragma unroll
        for (int kk = 0; kk < 4; ++kk) {
            const int byte = n * 128 + ((kk * 32 + h * 16) ^ ((n & 7) << 4));
            const bf16x8 a2 = *reinterpret_cast<const bf16x8*>(sl + byte);
            acc2A = __builtin_amdgcn_mfma_f32_32x32x16_bf16(a2, b2f[kk][0], acc2A, 0, 0, 0);
            acc2B = __builtin_amdgcn_mfma_f32_32x32x16_bf16(a2, b2f[kk][1], acc2B, 0, 0, 0);
        }
        __builtin_amdgcn_wave_barrier();
#pragma unroll
        for (int j = 0; j < 16; ++j) {
            const int m = crow(j, h);
            const int eat = e0 + m;
            if (!GUARD || eat < E) {
                const unsigned row = (unsigned)lds_row[el0 + m];
                if (F16) {
                    __half* const dst = reinterpret_cast<__half*>(agg) + row * 64u;
                    atom_pk_add_f16(dst + 2 * n, pk_f16(acc2A[j], acc2B[j]));
                } else {
                    float* const dst = reinterpret_cast<float*>(agg) + row * 64u;
                    atomicAdd(dst + 2 * n,     acc2A[j]);
                    atomicAdd(dst + 2 * n + 1, acc2B[j]);
                }
            }
        }
    }
}

// ===========================================================================
extern "C" void kernel_launch(void* const* d_in, const int* in_sizes, int n_in,
                              void* d_out, int out_size, void* d_ws, size_t ws_size,
                              hipStream_t stream) {
    const float* x      = (const float*)d_in[0];
    const float* rbf    = (const float*)d_in[2];
    const int*   ei     = (const int*)d_in[3];
    const float* W1 = (const float*)d_in[4];
    const float* b1 = (const float*)d_in[5];
    const float* W2 = (const float*)d_in[6];
    const float* b2 = (const float*)d_in[7];
    const float* W3 = (const float*)d_in[8];
    const float* b3 = (const float*)d_in[9];
    const float* W4 = (const float*)d_in[10];
    const float* b4 = (const float*)d_in[11];
    float* out = (float*)d_out;

    const int E  = (int)(in_sizes[3] / 2);
    const int nn = in_sizes[0] / EMBED;
    const int nscan = (nn + SCAN_TILE - 1) / SCAN_TILE;
    const int nsPad = (nscan + 63) & ~63;

    // ws layout: smsg (E*128 B) | offsets (nn+1) | counts (nn) | bsums
    const size_t msgBytes = (size_t)E * 128;
    unsigned* smsg  = (unsigned*)d_ws;
    int* offsets    = (int*)((char*)d_ws + msgBytes);
    int* counts     = offsets + nn + 1;
    int* bsums      = counts + nn;
    const size_t neededSort = msgBytes + sizeof(int) * ((size_t)(nn + 1) + nn + nsPad);

    const int nfull = E / 256;
    const int rem   = E - nfull * 256;
    const unsigned egrid = (unsigned)((E + 255) / 256);

    if (ws_size >= neededSort) {
        // ---- CSR offsets ----
        hipMemsetAsync(counts, 0, sizeof(int) * nn, stream);
        k_hist<<<dim3(egrid), dim3(256), 0, stream>>>(ei, counts, E);
        k_scan1<<<dim3((unsigned)nscan), dim3(256), 0, stream>>>(counts, offsets, bsums, nn);
        k_scan2<<<dim3(1), dim3(256), 0, stream>>>(bsums, nscan);
        k_scan3<<<dim3((unsigned)nscan), dim3(256), 0, stream>>>(offsets, bsums, counts, nn, E);
        // ---- phase 1: GEMM1 + SiLU, sorted nontemporal stores ----
        if (nfull)
            edge1_lite<false><<<dim3(nfull), dim3(256), 0, stream>>>(
                rbf, ei, W1, b1, offsets, counts, smsg, 0, E);
        if (rem)
            edge1_lite<true><<<dim3(1), dim3(256), 0, stream>>>(
                rbf, ei, W1, b1, offsets, counts, smsg, nfull * 256, E);
        // ---- phase 2a: grid-strided segment-sum + W2 -> agg in d_out ----
        k_agg2<<<dim3(2048), dim3(256), 0, stream>>>(
            smsg, offsets, W2, b2, out, nn);
        // ---- phase 2b: node MLP in place ----
        node_kernel<false><<<dim3(2048), dim3(256), 0, stream>>>(
            x, out, W3, b3, W4, b4, out, nn);
    } else if (ws_size >= (size_t)nn * EMBED * sizeof(__half)) {
        // ---- fallback: r12 pk-f16 atomic path (396 us validated) ----
        hipMemsetAsync(d_ws, 0, (size_t)nn * EMBED * sizeof(__half), stream);
        if (nfull)
            edge_kernel32<false, true><<<dim3(nfull), dim3(256), 0, stream>>>(
                rbf, ei, W1, b1, W2, b2, d_ws, 0, E);
        if (rem)
            edge_kernel32<true, true><<<dim3(1), dim3(256), 0, stream>>>(
                rbf, ei, W1, b1, W2, b2, d_ws, nfull * 256, E);
        node_kernel<true><<<dim3(2048), dim3(256), 0, stream>>>(
            x, d_ws, W3, b3, W4, b4, out, nn);
    } else {
        hipMemsetAsync(out, 0, (size_t)nn * EMBED * sizeof(float), stream);
        if (nfull)
            edge_kernel32<false, false><<<dim3(nfull), dim3(256), 0, stream>>>(
                rbf, ei, W1, b1, W2, b2, out, 0, E);
        if (rem)
            edge_kernel32<true, false><<<dim3(1), dim3(256), 0, stream>>>(
                rbf, ei, W1, b1, W2, b2, out, nfull * 256, E);
        node_kernel<false><<<dim3(2048), dim3(256), 0, stream>>>(
            x, out, W3, b3, W4, b4, out, nn);
    }
}

// Round 16
// 479.459 us; speedup vs baseline: 1.3384x; 1.1888x over previous
//
#include <hip/hip_runtime.h>
#include <hip/hip_bf16.h>

typedef __attribute__((ext_vector_type(8)))  short bf16x8;
typedef __attribute__((ext_vector_type(16))) float f32x16;

constexpr int EMBED = 64;
constexpr int RBF   = 16;

__device__ __forceinline__ short f2bf(float f) {
    __hip_bfloat16 h = __float2bfloat16(f);   // RNE
    return *reinterpret_cast<short*>(&h);
}
__device__ __forceinline__ float bf2f(short s) {
    unsigned u = ((unsigned)(unsigned short)s) << 16;
    return __uint_as_float(u);
}
__device__ __forceinline__ unsigned pk_bf(float lo, float hi) {
    unsigned l = (unsigned short)f2bf(lo);
    unsigned h = (unsigned short)f2bf(hi);
    return l | (h << 16);
}
__device__ __forceinline__ float silu(float x) {
    return x * __builtin_amdgcn_rcpf(1.0f + __expf(-x));
}

// bf16(pi), bf16(pi/2) (r10-validated angle constants)
constexpr float PI_BF  = 3.140625f;
constexpr float PI2_BF = 1.5703125f;

// fixed-point packing for u64 quad-channel atomics:
// field = round((msg + OFF) * SCALE), u16; node kernel: msg_sum = field/SCALE - deg*OFF
constexpr float OFF   = 4.0f;
constexpr float SCALE = 64.0f;
constexpr float INVSC = 1.0f / 64.0f;

// C/D row map for 32x32 MFMA (r12-validated)
__device__ __forceinline__ int crow(int j, int h) {
    return (j & 3) + 8 * (j >> 2) + 4 * h;
}

// ======================= edge kernel (r12 base + u64 quad atomics) =========
template <bool GUARD, bool QUAD>
__global__ __launch_bounds__(256, 2) void edge_kernel32(
    const float* __restrict__ rbf,
    const int* __restrict__ ei,
    const float* __restrict__ W1,
    const float* __restrict__ b1,
    const float* __restrict__ W2,
    const float* __restrict__ b2,
    unsigned long long* __restrict__ aggq,   // QUAD: nn x 16 u64
    unsigned* __restrict__ deg,              // QUAD: nn u32
    float* __restrict__ aggf,                // !QUAD: nn x 64 f32
    int e_base, int E)
{
    __shared__ __align__(16) short lds_s[4][32 * 64];  // 16 KB
    __shared__ int lds_row[256];
    __shared__ unsigned char lds_flag[256];
    __shared__ int wave_any[4];

    const int tid  = threadIdx.x;
    const int lane = tid & 63;
    const int wave = tid >> 6;
    const int n = lane & 31;
    const int h = lane >> 5;
    const int blk_e0 = e_base + blockIdx.x * 256;

    // ---- stage rows + self-loop flags + deg count ----
    {
        const int e = blk_e0 + tid;
        const bool v = !GUARD || (e < E);
        const int row = v ? ei[e] : 0;
        const int col = v ? ei[E + e] : 1;
        lds_row[tid]  = row;
        const bool fl = v && (row == col);
        lds_flag[tid] = fl;
        const unsigned long long m = __ballot(fl);
        if (lane == 0) wave_any[wave] = (m != 0ull);
        if (QUAD && v) atomicAdd(&deg[row], 1u);
    }
    __syncthreads();

    // ---- B fragments + folded biases (r12-validated) ----
    bf16x8 b1f[2];
    float  b1v[2], dlt[2], b2v[2];
#pragma unroll
    for (int hh = 0; hh < 2; ++hh) {
        const int ch = 2 * n + hh;
#pragma unroll
        for (int j = 0; j < 8; ++j)
            b1f[hh][j] = f2bf(W1[(h * 8 + j) * EMBED + ch]);
        const float w16 = bf2f(f2bf(W1[RBF * EMBED + ch]));
        b1v[hh] = b1[ch] + PI_BF * w16;          // angle==pi folded into bias
        dlt[hh] = (PI2_BF - PI_BF) * w16;        // self-loop correction
        b2v[hh] = b2[ch];
    }
    bf16x8 b2f[4][2];
#pragma unroll
    for (int kk = 0; kk < 4; ++kk)
#pragma unroll
        for (int hh = 0; hh < 2; ++hh) {
            const int ch = 2 * n + hh;
#pragma unroll
            for (int j = 0; j < 8; ++j)
                b2f[kk][hh][j] = f2bf(W2[(kk * 16 + h * 8 + j) * EMBED + ch]);
        }

    char* const sl = reinterpret_cast<char*>(lds_s[wave]);

#pragma unroll 1
    for (int mt = 0; mt < 2; ++mt) {
        const int e0  = blk_e0 + wave * 64 + mt * 32;
        if (GUARD && e0 >= E) break;
        const int el0 = wave * 64 + mt * 32;

        // ---- A1: edge m=n, k = h*8+j ----
        bf16x8 a1 = {};
        {
            const int ea = e0 + n;
            if (!GUARD || ea < E) {
                const float4 p0 = *reinterpret_cast<const float4*>(rbf + (long long)ea * RBF + h * 8);
                const float4 p1 = *reinterpret_cast<const float4*>(rbf + (long long)ea * RBF + h * 8 + 4);
                a1[0] = f2bf(p0.x); a1[1] = f2bf(p0.y); a1[2] = f2bf(p0.z); a1[3] = f2bf(p0.w);
                a1[4] = f2bf(p1.x); a1[5] = f2bf(p1.y); a1[6] = f2bf(p1.z); a1[7] = f2bf(p1.w);
            }
        }

        // ---- GEMM1, angle folded into bias ----
        f32x16 accA, accB;
#pragma unroll
        for (int j = 0; j < 16; ++j) { accA[j] = b1v[0]; accB[j] = b1v[1]; }
        accA = __builtin_amdgcn_mfma_f32_32x32x16_bf16(a1, b1f[0], accA, 0, 0, 0);
        accB = __builtin_amdgcn_mfma_f32_32x32x16_bf16(a1, b1f[1], accB, 0, 0, 0);

        if (wave_any[wave]) {
#pragma unroll
            for (int j = 0; j < 16; ++j) {
                const int m = crow(j, h);
                if (lds_flag[el0 + m]) { accA[j] += dlt[0]; accB[j] += dlt[1]; }
            }
        }

        // ---- SiLU + pk-bf16 swizzled LDS write ----
#pragma unroll
        for (int j = 0; j < 16; ++j) {
            const int m = crow(j, h);
            const unsigned u = pk_bf(silu(accA[j]), silu(accB[j]));
            *reinterpret_cast<unsigned*>(sl + m * 128 + ((4 * n) ^ ((m & 7) << 4))) = u;
        }
        __builtin_amdgcn_wave_barrier();

        // ---- GEMM2 ----
        f32x16 acc2A, acc2B;
#pragma unroll
        for (int j = 0; j < 16; ++j) { acc2A[j] = b2v[0]; acc2B[j] = b2v[1]; }
#pragma unroll
        for (int kk = 0; kk < 4; ++kk) {
            const int byte = n * 128 + ((kk * 32 + h * 16) ^ ((n & 7) << 4));
            const bf16x8 a2 = *reinterpret_cast<const bf16x8*>(sl + byte);
            acc2A = __builtin_amdgcn_mfma_f32_32x32x16_bf16(a2, b2f[kk][0], acc2A, 0, 0, 0);
            acc2B = __builtin_amdgcn_mfma_f32_32x32x16_bf16(a2, b2f[kk][1], acc2B, 0, 0, 0);
        }
        __builtin_amdgcn_wave_barrier();

        // ---- scatter: quad-channel u64 fixed-point atomics ----
        // lane n holds ch (2n, 2n+1); lanes (2q, 2q+1) together hold ch 4q..4q+3.
        // Pair lanes exchange packed u32s; even lane issues one u64 atomic.
#pragma unroll
        for (int j = 0; j < 16; ++j) {
            const int m = crow(j, h);
            const int eat = e0 + m;
            if (!GUARD || eat < E) {
                const unsigned row = (unsigned)lds_row[el0 + m];
                if (QUAD) {
                    const unsigned fa = min(__float2uint_rn((acc2A[j] + OFF) * SCALE), 0xFFFFu);
                    const unsigned fb = min(__float2uint_rn((acc2B[j] + OFF) * SCALE), 0xFFFFu);
                    const unsigned my = fa | (fb << 16);
                    const unsigned partner = __shfl_xor(my, 1, 64);
                    if ((n & 1) == 0) {
                        const unsigned long long v =
                            ((unsigned long long)partner << 32) | (unsigned long long)my;
                        atomicAdd(aggq + (size_t)row * 16u + (unsigned)(n >> 1), v);
                    }
                } else {
                    float* const dst = aggf + (size_t)row * 64u;
                    atomicAdd(dst + 2 * n,     acc2A[j]);
                    atomicAdd(dst + 2 * n + 1, acc2B[j]);
                }
            }
        }
    }
}

// ======================= node kernel, fixed-point agg read =================
__global__ __launch_bounds__(256) void node_kernel_q(
    const float* __restrict__ x,
    const unsigned long long* __restrict__ aggq,
    const unsigned* __restrict__ deg,
    const float* __restrict__ W3, const float* __restrict__ b3,
    const float* __restrict__ W4, const float* __restrict__ b4,
    float* __restrict__ out, int nn)
{
    __shared__ __align__(16) float lds_s[4][EMBED];
    const int lane = threadIdx.x & 63;
    const int wave = threadIdx.x >> 6;
    float w3c[EMBED], w4c[EMBED];
#pragma unroll
    for (int j = 0; j < EMBED; ++j) w3c[j] = W3[j * EMBED + lane];
#pragma unroll
    for (int j = 0; j < EMBED; ++j) w4c[j] = W4[j * EMBED + lane];
    const float b3v = b3[lane];
    const float b4v = b4[lane];
    const float4* s4 = reinterpret_cast<const float4*>(lds_s[wave]);
    const int wid = blockIdx.x * 4 + wave;
    const int nw  = gridDim.x * 4;
    for (int nid = wid; nid < nn; nid += nw) {
        // channel = lane: read u64 word lane>>2, field lane&3
        const unsigned long long v = aggq[(size_t)nid * 16u + (unsigned)(lane >> 2)];
        const unsigned fld = (unsigned)((v >> (16 * (lane & 3))) & 0xFFFFull);
        const float a = (float)fld * INVSC - (float)deg[nid] * OFF;

        lds_s[wave][lane] = a;
        __builtin_amdgcn_wave_barrier();
        float acc = b3v;
#pragma unroll
        for (int j4 = 0; j4 < EMBED / 4; ++j4) {
            const float4 sv = s4[j4];
            acc = fmaf(sv.x, w3c[4 * j4 + 0], acc);
            acc = fmaf(sv.y, w3c[4 * j4 + 1], acc);
            acc = fmaf(sv.z, w3c[4 * j4 + 2], acc);
            acc = fmaf(sv.w, w3c[4 * j4 + 3], acc);
        }
        const float s = acc * __builtin_amdgcn_rcpf(1.0f + __expf(-acc));
        __builtin_amdgcn_wave_barrier();
        lds_s[wave][lane] = s;
        __builtin_amdgcn_wave_barrier();
        float acc2 = b4v;
#pragma unroll
        for (int j4 = 0; j4 < EMBED / 4; ++j4) {
            const float4 sv = s4[j4];
            acc2 = fmaf(sv.x, w4c[4 * j4 + 0], acc2);
            acc2 = fmaf(sv.y, w4c[4 * j4 + 1], acc2);
            acc2 = fmaf(sv.z, w4c[4 * j4 + 2], acc2);
            acc2 = fmaf(sv.w, w4c[4 * j4 + 3], acc2);
        }
        __builtin_amdgcn_wave_barrier();
        const long long base = (long long)nid * EMBED + lane;
        out[base] = x[base] + acc2;
    }
}

// fp32-agg node kernel (fallback path; in-place capable)
__global__ __launch_bounds__(256) void node_kernel_f(
    const float* __restrict__ x, const float* __restrict__ aggv,
    const float* __restrict__ W3, const float* __restrict__ b3,
    const float* __restrict__ W4, const float* __restrict__ b4,
    float* __restrict__ out, int nn)
{
    __shared__ __align__(16) float lds_s[4][EMBED];
    const int lane = threadIdx.x & 63;
    const int wave = threadIdx.x >> 6;
    float w3c[EMBED], w4c[EMBED];
#pragma unroll
    for (int j = 0; j < EMBED; ++j) w3c[j] = W3[j * EMBED + lane];
#pragma unroll
    for (int j = 0; j < EMBED; ++j) w4c[j] = W4[j * EMBED + lane];
    const float b3v = b3[lane];
    const float b4v = b4[lane];
    const float4* s4 = reinterpret_cast<const float4*>(lds_s[wave]);
    const int wid = blockIdx.x * 4 + wave;
    const int nw  = gridDim.x * 4;
    for (int n = wid; n < nn; n += nw) {
        const long long base = (long long)n * EMBED + lane;
        const float a = aggv[base];
        lds_s[wave][lane] = a;
        __builtin_amdgcn_wave_barrier();
        float acc = b3v;
#pragma unroll
        for (int j4 = 0; j4 < EMBED / 4; ++j4) {
            const float4 sv = s4[j4];
            acc = fmaf(sv.x, w3c[4 * j4 + 0], acc);
            acc = fmaf(sv.y, w3c[4 * j4 + 1], acc);
            acc = fmaf(sv.z, w3c[4 * j4 + 2], acc);
            acc = fmaf(sv.w, w3c[4 * j4 + 3], acc);
        }
        const float s = acc * __builtin_amdgcn_rcpf(1.0f + __expf(-acc));
        __builtin_amdgcn_wave_barrier();
        lds_s[wave][lane] = s;
        __builtin_amdgcn_wave_barrier();
        float acc2 = b4v;
#pragma unroll
        for (int j4 = 0; j4 < EMBED / 4; ++j4) {
            const float4 sv = s4[j4];
            acc2 = fmaf(sv.x, w4c[4 * j4 + 0], acc2);
            acc2 = fmaf(sv.y, w4c[4 * j4 + 1], acc2);
            acc2 = fmaf(sv.z, w4c[4 * j4 + 2], acc2);
            acc2 = fmaf(sv.w, w4c[4 * j4 + 3], acc2);
        }
        __builtin_amdgcn_wave_barrier();
        out[base] = x[base] + acc2;
    }
}

// ===========================================================================
extern "C" void kernel_launch(void* const* d_in, const int* in_sizes, int n_in,
                              void* d_out, int out_size, void* d_ws, size_t ws_size,
                              hipStream_t stream) {
    const float* x      = (const float*)d_in[0];
    const float* rbf    = (const float*)d_in[2];
    const int*   ei     = (const int*)d_in[3];
    const float* W1 = (const float*)d_in[4];
    const float* b1 = (const float*)d_in[5];
    const float* W2 = (const float*)d_in[6];
    const float* b2 = (const float*)d_in[7];
    const float* W3 = (const float*)d_in[8];
    const float* b3 = (const float*)d_in[9];
    const float* W4 = (const float*)d_in[10];
    const float* b4 = (const float*)d_in[11];
    float* out = (float*)d_out;

    const int E  = (int)(in_sizes[3] / 2);
    const int nn = in_sizes[0] / EMBED;

    // ws layout: aggq u64[nn*16] | deg u32[nn]
    const size_t aggqBytes = (size_t)nn * 16 * sizeof(unsigned long long);
    const size_t degBytes  = (size_t)nn * sizeof(unsigned);
    unsigned long long* aggq = (unsigned long long*)d_ws;
    unsigned* deg = (unsigned*)((char*)d_ws + aggqBytes);

    const int nfull = E / 256;
    const int rem   = E - nfull * 256;

    if (ws_size >= aggqBytes + degBytes) {
        hipMemsetAsync(d_ws, 0, aggqBytes + degBytes, stream);
        if (nfull)
            edge_kernel32<false, true><<<dim3(nfull), dim3(256), 0, stream>>>(
                rbf, ei, W1, b1, W2, b2, aggq, deg, nullptr, 0, E);
        if (rem)
            edge_kernel32<true, true><<<dim3(1), dim3(256), 0, stream>>>(
                rbf, ei, W1, b1, W2, b2, aggq, deg, nullptr, nfull * 256, E);
        node_kernel_q<<<dim3(2048), dim3(256), 0, stream>>>(
            x, aggq, deg, W3, b3, W4, b4, out, nn);
    } else {
        // fallback: fp32 atomics into d_out, node MLP in place
        hipMemsetAsync(out, 0, (size_t)nn * EMBED * sizeof(float), stream);
        if (nfull)
            edge_kernel32<false, false><<<dim3(nfull), dim3(256), 0, stream>>>(
                rbf, ei, W1, b1, W2, b2, nullptr, nullptr, out, 0, E);
        if (rem)
            edge_kernel32<true, false><<<dim3(1), dim3(256), 0, stream>>>(
                rbf, ei, W1, b1, W2, b2, nullptr, nullptr, out, nfull * 256, E);
        node_kernel_f<<<dim3(2048), dim3(256), 0, stream>>>(
            x, out, W3, b3, W4, b4, out, nn);
    }
}